// Round 1
// 587.724 us; speedup vs baseline: 1.0373x; 1.0373x over previous
//
#include <hip/hip_runtime.h>
#include <hip/hip_bf16.h>

#define N_NODES 100000
#define N_EDGES 3200000
#define D 256
#define RSH 7
#define RPB 128                                  // rows per bucket = 1<<RSH
#define NB ((N_NODES + RPB - 1) / RPB)           // 782 coarse buckets
#define FILL_CH 8192                             // edges per block in bin/hist
#define NBLK_E ((N_EDGES + FILL_CH - 1) / FILL_CH)  // 391

typedef __attribute__((ext_vector_type(8))) short short8;   // 8 bf16 (4 VGPRs)
typedef __attribute__((ext_vector_type(4))) float floatx4;  // MFMA C/D

__device__ __forceinline__ unsigned short f32_to_bf16_rne(float f) {
    unsigned int u = __float_as_uint(f);
    u += 0x7FFFu + ((u >> 16) & 1u);
    return (unsigned short)(u >> 16);
}
__device__ __forceinline__ float bf16_bits_to_f32(unsigned short b) {
    return __uint_as_float(((unsigned int)b) << 16);
}
__device__ __forceinline__ float blo(unsigned int x) { return __uint_as_float(x << 16); }
__device__ __forceinline__ float bhi(unsigned int x) { return __uint_as_float(x & 0xFFFF0000u); }

// ---------------- W (fp32 [K][N]) -> bf16 MFMA-B-fragment order --------------
__global__ __launch_bounds__(256) void convert_w_k(const float* __restrict__ w,
                                                   unsigned short* __restrict__ wsw) {
    int t = blockIdx.x * 256 + threadIdx.x;
    int j     = t & 7;
    int lane  = (t >> 3) & 63;
    int kstep = (t >> 9) & 7;
    int ntile = t >> 12;
    int k = kstep * 32 + (lane >> 4) * 8 + j;
    int n = ntile * 16 + (lane & 15);
    wsw[t] = f32_to_bf16_rne(w[k * D + n]);
}

// ---------------- xw = x @ W (bf16 MFMA), output bf16 ------------------------
// 512 threads / 8 waves per block: 128 rows/block, 782 blocks (3.05 rounds of
// 256 CUs). 128 KiB LDS still means 1 block/CU, but now 2 waves/SIMD (was 1)
// and W is staged half as many times.
__global__ __launch_bounds__(512) void gemm_xw_k(const float* __restrict__ x,
                                                 const unsigned short* __restrict__ wsw,
                                                 unsigned short* __restrict__ xwb) {
    __shared__ uint4 wlds[8192];  // 128 KiB swizzled bf16 W
    const int tid = threadIdx.x;
#pragma unroll
    for (int i = 0; i < 16; ++i) {
        int idx = i * 512 + tid;
        wlds[idx] = ((const uint4*)wsw)[idx];
    }
    __syncthreads();

    const int lane = tid & 63;
    const int wave = tid >> 6;            // 0..7
    const int q    = lane >> 4;
    const int ml   = lane & 15;
    const long rowBase = (long)blockIdx.x * 128 + wave * 16;
    long arow = rowBase + ml;
    if (arow >= N_NODES) arow = 0;
    const float* xr = x + arow * (long)D;

    floatx4 acc[16];
#pragma unroll
    for (int i = 0; i < 16; ++i) acc[i] = (floatx4){0.f, 0.f, 0.f, 0.f};

    const short8* wfrag = (const short8*)wlds;

#pragma unroll
    for (int ks = 0; ks < 8; ++ks) {
        const float4 a0 = *(const float4*)(xr + ks * 32 + q * 8);
        const float4 a1 = *(const float4*)(xr + ks * 32 + q * 8 + 4);
        short8 af;
        af[0] = (short)f32_to_bf16_rne(a0.x);
        af[1] = (short)f32_to_bf16_rne(a0.y);
        af[2] = (short)f32_to_bf16_rne(a0.z);
        af[3] = (short)f32_to_bf16_rne(a0.w);
        af[4] = (short)f32_to_bf16_rne(a1.x);
        af[5] = (short)f32_to_bf16_rne(a1.y);
        af[6] = (short)f32_to_bf16_rne(a1.z);
        af[7] = (short)f32_to_bf16_rne(a1.w);
#pragma unroll
        for (int nt = 0; nt < 16; ++nt) {
            acc[nt] = __builtin_amdgcn_mfma_f32_16x16x32_bf16(
                af, wfrag[(nt * 8 + ks) * 64 + lane], acc[nt], 0, 0, 0);
        }
    }

#pragma unroll
    for (int nt = 0; nt < 16; ++nt) {
#pragma unroll
        for (int r = 0; r < 4; ++r) {
            long orow = rowBase + q * 4 + r;
            if (orow < N_NODES)
                xwb[orow * (long)D + nt * 16 + ml] = f32_to_bf16_rne(acc[nt][r]);
        }
    }
}

// ---------------- coarse-bucket histogram (LDS-aggregated) -------------------
__global__ __launch_bounds__(256) void bhist_k(const int* __restrict__ erow,
                                               int* __restrict__ counts) {
    __shared__ int h[NB];
    const int tid = threadIdx.x;
    for (int i = tid; i < NB; i += 256) h[i] = 0;
    __syncthreads();
    const int s = blockIdx.x * FILL_CH;
    const int e = min(s + FILL_CH, N_EDGES);
    for (int i = s + tid; i < e; i += 256) atomicAdd(&h[erow[i] >> RSH], 1);
    __syncthreads();
    for (int i = tid; i < NB; i += 256)
        if (h[i] > 0) atomicAdd(&counts[i], h[i]);
}

// ---------------- scan NB bucket counts (1 block of 1024) --------------------
__global__ __launch_bounds__(1024) void bscan_k(const int* __restrict__ counts,
                                                int* __restrict__ bbase,
                                                int* __restrict__ bcursor) {
    __shared__ int sc[1024];
    const int t = threadIdx.x;
    int v = (t < NB) ? counts[t] : 0;
    sc[t] = v;
    __syncthreads();
    for (int o = 1; o < 1024; o <<= 1) {
        int add = (t >= o) ? sc[t - o] : 0;
        __syncthreads();
        sc[t] += add;
        __syncthreads();
    }
    int excl = sc[t] - v;
    if (t < NB) { bbase[t] = excl; bcursor[t] = excl; }
    if (t == NB - 1) bbase[NB] = sc[t];
}

// ---------------- bin edges into coarse buckets (packed u64 records) ---------
// rec = row_local<<33 | val_bf16<<17 | col
__global__ __launch_bounds__(256) void binfill_k(const int* __restrict__ erow,
                                                 const int* __restrict__ ecol,
                                                 const float* __restrict__ eval,
                                                 int* __restrict__ bcursor,
                                                 unsigned long long* __restrict__ recs) {
    __shared__ int h[NB];
    __shared__ int lcur[NB];
    const int tid = threadIdx.x;
    for (int i = tid; i < NB; i += 256) h[i] = 0;
    __syncthreads();
    const int s = blockIdx.x * FILL_CH;
    const int e = min(s + FILL_CH, N_EDGES);
    for (int i = s + tid; i < e; i += 256) atomicAdd(&h[erow[i] >> RSH], 1);
    __syncthreads();
    for (int i = tid; i < NB; i += 256) {
        int cnt = h[i];
        lcur[i] = (cnt > 0) ? atomicAdd(&bcursor[i], cnt) : 0;
    }
    __syncthreads();
    for (int i = s + tid; i < e; i += 256) {
        int r = erow[i];
        int b = r >> RSH;
        int pos = atomicAdd(&lcur[b], 1);
        unsigned long long rec =
            ((unsigned long long)(r & (RPB - 1)) << 33) |
            ((unsigned long long)f32_to_bf16_rne(eval[i]) << 17) |
            (unsigned int)ecol[i];
        recs[pos] = rec;
    }
}

// ---------------- per-bucket counting sort to full row order -----------------
__global__ __launch_bounds__(256) void bsort_k(const int* __restrict__ bbase,
                                               const unsigned long long* __restrict__ recs,
                                               int* __restrict__ offsets,
                                               unsigned int* __restrict__ cs,
                                               unsigned short* __restrict__ vs) {
    __shared__ int hist[RPB];
    __shared__ int cur[RPB];
    __shared__ int sc[RPB];
    const int t = threadIdx.x;
    const int b = blockIdx.x;
    const int base = bbase[b];
    const int endp = bbase[b + 1];

    if (t < RPB) hist[t] = 0;
    __syncthreads();
    for (int i = base + t; i < endp; i += 256)
        atomicAdd(&hist[(int)(recs[i] >> 33)], 1);
    __syncthreads();

    if (t < RPB) sc[t] = hist[t];
    __syncthreads();
    for (int o = 1; o < RPB; o <<= 1) {
        int add = (t >= o && t < RPB) ? sc[t - o] : 0;
        __syncthreads();
        if (t < RPB) sc[t] += add;
        __syncthreads();
    }
    if (t < RPB) {
        int excl = sc[t] - hist[t];
        cur[t] = excl;
        int r = (b << RSH) + t;
        if (r <= N_NODES) offsets[r] = base + excl;   // r==N_NODES covered by last bucket
    }
    __syncthreads();

    for (int i = base + t; i < endp; i += 256) {
        unsigned long long rec = recs[i];
        int rl = (int)(rec >> 33);
        int pos = base + atomicAdd(&cur[rl], 1);
        cs[pos] = (unsigned int)(rec & 0x1FFFFu);
        vs[pos] = (unsigned short)((rec >> 17) & 0xFFFFu);
    }
}

// ---------------- segment reduce: out[r] = relu(sum v * xwb[c]) --------------
// one wave per node. Fast path: full groups of 8 pairs (16 edges) with NO
// masking and 8 independent uint4 gathers in flight (latency hiding); masked
// scalar-pair tail only for the remainder. Live set kept <= ~64 VGPR so
// occupancy stays at 8 waves/SIMD.
__global__ __launch_bounds__(256) void aggregate_k(const unsigned short* __restrict__ xwb,
                                                   const int* __restrict__ offsets,
                                                   const unsigned int* __restrict__ cs,
                                                   const unsigned short* __restrict__ vs,
                                                   float* __restrict__ out) {
    const int wave = threadIdx.x >> 6;
    const int lane = threadIdx.x & 63;
    const int r = blockIdx.x * 4 + wave;
    if (r >= N_NODES) return;

    const int start = offsets[r];
    const int end   = offsets[r + 1];
    const int half  = lane >> 5;
    const int hl    = lane & 31;

    float acc[8];
#pragma unroll
    for (int k = 0; k < 8; ++k) acc[k] = 0.f;

#pragma unroll 1
    for (int jb = start; jb < end; jb += 64) {
        int j = jb + lane;
        unsigned int c = 0;
        float v = 0.f;
        if (j < end) {
            c = cs[j];
            v = bf16_bits_to_f32(vs[j]);
        }
        const int cnt = min(64, end - jb);
        const int pairs = (cnt + 1) >> 1;
        const int hp = cnt >> 1;          // # of full (unmasked) pairs
        int t = 0;

#define FMA8(qv, bv)                                                           \
        acc[0] += bv * blo(qv.x); acc[1] += bv * bhi(qv.x);                    \
        acc[2] += bv * blo(qv.y); acc[3] += bv * bhi(qv.y);                    \
        acc[4] += bv * blo(qv.z); acc[5] += bv * bhi(qv.z);                    \
        acc[6] += bv * blo(qv.w); acc[7] += bv * bhi(qv.w);
#define SLOTF(s, qv, bv)                                                       \
        {                                                                      \
            int src = 2 * (t + (s)) + half;                                    \
            unsigned int bc = (unsigned int)__shfl((int)c, src);               \
            bv = __shfl(v, src);                                               \
            qv = ((const uint4*)(xwb + (size_t)bc * D))[hl];                   \
        }

        // ---- 8-deep unmasked fast path (16 edges / iter) ----
#pragma unroll 1
        for (; t + 8 <= hp; t += 8) {
            uint4 q0, q1, q2, q3, q4, q5, q6, q7;
            float b0, b1, b2, b3, b4, b5, b6, b7;
            SLOTF(0, q0, b0) SLOTF(1, q1, b1) SLOTF(2, q2, b2) SLOTF(3, q3, b3)
            SLOTF(4, q4, b4) SLOTF(5, q5, b5) SLOTF(6, q6, b6) SLOTF(7, q7, b7)
            FMA8(q0, b0) FMA8(q1, b1) FMA8(q2, b2) FMA8(q3, b3)
            FMA8(q4, b4) FMA8(q5, b5) FMA8(q6, b6) FMA8(q7, b7)
        }
        // ---- 4-deep unmasked (8 edges) ----
        if (t + 4 <= hp) {
            uint4 q0, q1, q2, q3;
            float b0, b1, b2, b3;
            SLOTF(0, q0, b0) SLOTF(1, q1, b1) SLOTF(2, q2, b2) SLOTF(3, q3, b3)
            FMA8(q0, b0) FMA8(q1, b1) FMA8(q2, b2) FMA8(q3, b3)
            t += 4;
        }
#undef SLOTF

        // ---- masked scalar-pair tail ----
#pragma unroll 1
        for (; t < pairs; ++t) {
            int src = 2 * t + half;
            int srcc = min(src, cnt - 1);
            unsigned int bc = (unsigned int)__shfl((int)c, srcc);
            float bb = __shfl(v, srcc);
            float bv = (src < cnt) ? bb : 0.f;
            uint4 q = ((const uint4*)(xwb + (size_t)bc * D))[hl];
            FMA8(q, bv)
        }
#undef FMA8
    }

    // combine even/odd halves (lane l and l^32 hold the same columns)
#pragma unroll
    for (int k = 0; k < 8; ++k) acc[k] += __shfl_xor(acc[k], 32);

    // redistribute: lane l writes cols 4l..4l+3 (source lane l>>1)
    const int s = lane >> 1;
    const int par = lane & 1;
    float4 o;
    {
        float a0 = __shfl(acc[0], s), b0 = __shfl(acc[4], s);
        float a1 = __shfl(acc[1], s), b1 = __shfl(acc[5], s);
        float a2 = __shfl(acc[2], s), b2 = __shfl(acc[6], s);
        float a3 = __shfl(acc[3], s), b3 = __shfl(acc[7], s);
        o.x = par ? b0 : a0;
        o.y = par ? b1 : a1;
        o.z = par ? b2 : a2;
        o.w = par ? b3 : a3;
    }
    o.x = fmaxf(o.x, 0.f);
    o.y = fmaxf(o.y, 0.f);
    o.z = fmaxf(o.z, 0.f);
    o.w = fmaxf(o.w, 0.f);
    ((float4*)(out + (size_t)r * D))[lane] = o;
}

extern "C" void kernel_launch(void* const* d_in, const int* in_sizes, int n_in,
                              void* d_out, int out_size, void* d_ws, size_t ws_size,
                              hipStream_t stream) {
    const float* x    = (const float*)d_in[0];
    const float* w    = (const float*)d_in[1];
    const int*   erow = (const int*)d_in[2];
    const int*   ecol = (const int*)d_in[3];
    const float* eval = (const float*)d_in[4];
    float* out = (float*)d_out;

    // ---- workspace layout (~96.6 MB) ----
    char* p = (char*)d_ws;
    auto align = [](size_t v) { return (v + 255) & ~(size_t)255; };

    unsigned short* xwb = (unsigned short*)p;                  // 51.2 MB
    p += align((size_t)N_NODES * D * sizeof(unsigned short));
    unsigned short* wsw = (unsigned short*)p;                  // 128 KiB
    p += align((size_t)D * D * sizeof(unsigned short));
    int* bcounts = (int*)p;  p += align((size_t)NB * sizeof(int));
    int* bbase   = (int*)p;  p += align((size_t)(NB + 1) * sizeof(int));
    int* bcursor = (int*)p;  p += align((size_t)NB * sizeof(int));
    unsigned long long* recs = (unsigned long long*)p;         // 25.6 MB
    p += align((size_t)N_EDGES * sizeof(unsigned long long));
    unsigned int*   cs = (unsigned int*)p;    p += align((size_t)N_EDGES * 4);  // 12.8 MB
    unsigned short* vs = (unsigned short*)p;  p += align((size_t)N_EDGES * 2);  // 6.4 MB
    int* offsets = (int*)p;  p += align((size_t)(N_NODES + 1) * sizeof(int));   // 400 KB

    convert_w_k<<<(D * D) / 256, 256, 0, stream>>>(w, wsw);
    gemm_xw_k<<<(N_NODES + 127) / 128, 512, 0, stream>>>(x, wsw, xwb);
    hipMemsetAsync(bcounts, 0, (size_t)NB * sizeof(int), stream);
    bhist_k<<<NBLK_E, 256, 0, stream>>>(erow, bcounts);
    bscan_k<<<1, 1024, 0, stream>>>(bcounts, bbase, bcursor);
    binfill_k<<<NBLK_E, 256, 0, stream>>>(erow, ecol, eval, bcursor, recs);
    bsort_k<<<NB, 256, 0, stream>>>(bbase, recs, offsets, cs, vs);
    aggregate_k<<<(N_NODES + 3) / 4, 256, 0, stream>>>(xwb, offsets, cs, vs, out);
}